// Round 2
// baseline (586.638 us; speedup 1.0000x reference)
//
#include <hip/hip_runtime.h>
#include <hip/hip_bf16.h>

#define HIDDEN 8192
#define NHEADS 64
#define NKV 8
#define HD 128
#define BATCH 32
#define PADLEN 2048

// ---------------------------------------------------------------------------
// global_load_lds helper: DMA 16B/lane global->LDS. LDS dest = wave-uniform
// base + lane*16 (hardware-defined); global src is per-lane.
// ---------------------------------------------------------------------------
__device__ __forceinline__ void gld16(const float* g, float* l) {
    __builtin_amdgcn_global_load_lds(
        (const __attribute__((address_space(1))) void*)g,
        (__attribute__((address_space(3))) void*)l,
        16, 0, 0);
}

// ---------------------------------------------------------------------------
// Fused skinny GEMM: P[kb] += X[32][8192-chunk] @ {W0|W1|W2}.
// x is wave-uniform -> scalar s_load path (no LDS, no DS-pipe cost).
// No atomics: each k-split block writes its partial slice to P[kb];
// reduce_split sums the 32 splits afterwards.
// Sections by blockIdx.x: cb<16 -> W0 (N=8192), 16-17 -> W1, 18-19 -> W2.
// ---------------------------------------------------------------------------
#define KC 256
#define QSEC 262144          // 32*8192
#define KSEC 294912          // QSEC + 32*1024
#define QKV_STRIDE 327680    // QSEC + 2*32*1024

__global__ __launch_bounds__(256) void gemm_fused(const float* __restrict__ X,
                                                  const float* __restrict__ W0,
                                                  const float* __restrict__ W1,
                                                  const float* __restrict__ W2,
                                                  float* __restrict__ P,
                                                  size_t pstride) {
    const int tid = threadIdx.x;
    const int cb = blockIdx.x, kb = blockIdx.y;
    const int k0 = kb * KC;

    const float* W;
    int N2, so, colbase;
    if (cb < 16)      { W = W0; N2 = 8192; so = 0;    colbase = cb * 512; }
    else if (cb < 18) { W = W1; N2 = 1024; so = QSEC; colbase = (cb - 16) * 512; }
    else              { W = W2; N2 = 1024; so = KSEC; colbase = (cb - 18) * 512; }

    const int c0 = colbase + tid * 2;
    float2 acc[BATCH];
#pragma unroll
    for (int b = 0; b < BATCH; ++b) acc[b] = make_float2(0.f, 0.f);

    const float* wp = W + (size_t)k0 * N2 + c0;
    for (int kk = 0; kk < KC; kk += 4) {
        float2 w0 = *(const float2*)(wp);
        float2 w1 = *(const float2*)(wp + N2);
        float2 w2 = *(const float2*)(wp + 2 * (size_t)N2);
        float2 w3 = *(const float2*)(wp + 3 * (size_t)N2);
        wp += 4 * (size_t)N2;
        const float* xk = X + k0 + kk;
#pragma unroll
        for (int b = 0; b < BATCH; ++b) {
            float4 xv = *(const float4*)(xk + (size_t)b * HIDDEN);  // uniform -> s_load
            acc[b].x = fmaf(xv.x, w0.x, acc[b].x);
            acc[b].y = fmaf(xv.x, w0.y, acc[b].y);
            acc[b].x = fmaf(xv.y, w1.x, acc[b].x);
            acc[b].y = fmaf(xv.y, w1.y, acc[b].y);
            acc[b].x = fmaf(xv.z, w2.x, acc[b].x);
            acc[b].y = fmaf(xv.z, w2.y, acc[b].y);
            acc[b].x = fmaf(xv.w, w3.x, acc[b].x);
            acc[b].y = fmaf(xv.w, w3.y, acc[b].y);
        }
    }
    float* pdst = P + (size_t)kb * pstride + so + c0;
#pragma unroll
    for (int b = 0; b < BATCH; ++b)
        *(float2*)(pdst + (size_t)b * N2) = acc[b];
}

// out[i] = sum_s P[s][i]
__global__ __launch_bounds__(256) void reduce_split(const float* __restrict__ P,
                                                    float* __restrict__ out,
                                                    int nelem, size_t pstride) {
    int i = (blockIdx.x * 256 + threadIdx.x) * 4;
    if (i >= nelem) return;
    float4 a = *(const float4*)(P + i);
#pragma unroll 4
    for (int s = 1; s < 32; ++s) {
        float4 b = *(const float4*)(P + (size_t)s * pstride + i);
        a.x += b.x; a.y += b.y; a.z += b.z; a.w += b.w;
    }
    *(float4*)(out + i) = a;
}

// ---------------------------------------------------------------------------
// Rotary: rows 0..2047 = q rows (32*64), rows 2048..2303 = k rows (32*8).
// ---------------------------------------------------------------------------
#define RROWS 16
__global__ __launch_bounds__(128) void rotary_all(const float* __restrict__ qin,
                                                  const float* __restrict__ kin,
                                                  const float* __restrict__ rot,
                                                  float* __restrict__ qout,
                                                  float* __restrict__ kout) {
    __shared__ float rows[RROWS][HD];
    const int tid = threadIdx.x;
    const int row0 = blockIdx.x * RROWS;

    for (int i = tid; i < RROWS * (HD / 4); i += 128) {
        int r = i >> 5;
        int d4 = i & 31;
        int gr = row0 + r;
        const float* src = (gr < BATCH * NHEADS)
                               ? (qin + (size_t)gr * HD)
                               : (kin + (size_t)(gr - BATCH * NHEADS) * HD);
        *(float4*)&rows[r][d4 * 4] = *(const float4*)(src + d4 * 4);
    }
    __syncthreads();

    float acc[RROWS];
#pragma unroll
    for (int r = 0; r < RROWS; ++r) acc[r] = 0.f;

    for (int d4 = 0; d4 < HD; d4 += 4) {
        float r0 = rot[(size_t)(d4 + 0) * HD + tid];
        float r1 = rot[(size_t)(d4 + 1) * HD + tid];
        float r2 = rot[(size_t)(d4 + 2) * HD + tid];
        float r3 = rot[(size_t)(d4 + 3) * HD + tid];
#pragma unroll
        for (int r = 0; r < RROWS; ++r) {
            float4 xv = *(const float4*)&rows[r][d4];
            acc[r] = fmaf(xv.x, r0, acc[r]);
            acc[r] = fmaf(xv.y, r1, acc[r]);
            acc[r] = fmaf(xv.z, r2, acc[r]);
            acc[r] = fmaf(xv.w, r3, acc[r]);
        }
    }
#pragma unroll
    for (int r = 0; r < RROWS; ++r) {
        int gr = row0 + r;
        float* dst = (gr < BATCH * NHEADS)
                         ? (qout + (size_t)gr * HD)
                         : (kout + (size_t)(gr - BATCH * NHEADS) * HD);
        dst[tid] = acc[r];
    }
}

// ---------------------------------------------------------------------------
// Flash-decode attention, TILE=64, double-buffered global_load_lds staging.
// 256 blocks = (b,kv); 512 thr = 8 waves; wave = one q-head.
// q replicated in 128 VGPRs; scores: lane = tile row; p stays in registers
// (phase B broadcasts via uniform-index shfl = v_readlane).
// K staged with XOR swizzle applied at the GLOBAL source (DMA dest is linear).
// One barrier per tile; prefetch overlaps compute, drained by the barrier's
// implicit vmcnt(0).
// ---------------------------------------------------------------------------
#define TILE 64
__global__ __launch_bounds__(512) void attn_decode(const float* __restrict__ qr,
                                                   const float* __restrict__ kr,
                                                   const float* __restrict__ vnew,
                                                   const float* __restrict__ kcache,
                                                   const float* __restrict__ vcache,
                                                   const int* __restrict__ sp_ptr,
                                                   float* __restrict__ attn_out) {
    __shared__ float4 ktA[TILE][32], vtA[TILE][32];
    __shared__ float4 ktB[TILE][32], vtB[TILE][32];

    const int tid = threadIdx.x;
    const int wv = tid >> 6, ln = tid & 63;
    const int lo = ln & 31, hi = ln >> 5;
    const int b = blockIdx.x >> 3, kv = blockIdx.x & 7;
    const int sp = sp_ptr[0];
    const float scale = 0.08838834764831845f;  // 1/sqrt(128)

    const float* kbase = kcache + (size_t)(b * NKV + kv) * PADLEN * HD;
    const float* vbase = vcache + (size_t)(b * NKV + kv) * PADLEN * HD;
    const float* knew  = kr   + (size_t)(b * NKV + kv) * HD;
    const float* vnw   = vnew + (size_t)(b * NKV + kv) * HD;

    // q (this wave's head) replicated into registers
    float4 qreg[32];
    {
        const float4* qsrc = (const float4*)(qr + ((size_t)b * NHEADS + kv * 8 + wv) * HD);
#pragma unroll
        for (int i = 0; i < 32; ++i) qreg[i] = qsrc[i];
    }

    float m_run = -1e30f, dsum = 0.f;
    float4 acc = make_float4(0.f, 0.f, 0.f, 0.f);
    const int nt = (sp + TILE) >> 6;

    auto stage = [&](float4 (*kt)[32], float4 (*vt)[32], int t) {
        const int tile0 = t << 6;
#pragma unroll
        for (int i = 0; i < 4; ++i) {
            int sbase = (i * 8 + wv) << 6;   // wave-uniform slot base
            int s = sbase + ln;
            int r = s >> 5, j = s & 31;
            int gl = tile0 + r;
            int gls = gl < PADLEN ? gl : PADLEN - 1;
            const float* krow = (gl == sp) ? knew : (kbase + (size_t)gls * HD);
            const float* vrow = (gl == sp) ? vnw  : (vbase + (size_t)gls * HD);
            // K: pre-swizzled source so linear DMA produces swizzled LDS
            gld16(krow + ((j ^ (r & 31)) << 2), (float*)kt + (size_t)sbase * 4);
            gld16(vrow + (j << 2),              (float*)vt + (size_t)sbase * 4);
        }
    };

    auto compute = [&](float4 (*kt)[32], float4 (*vt)[32], int t) {
        // phase A: lane owns tile row ln
        float s0 = 0.f;
#pragma unroll
        for (int d4 = 0; d4 < 32; ++d4) {
            float4 kk = kt[ln][d4 ^ (ln & 31)];
            float4 qq = qreg[d4];
            s0 = fmaf(qq.x, kk.x, s0);
            s0 = fmaf(qq.y, kk.y, s0);
            s0 = fmaf(qq.z, kk.z, s0);
            s0 = fmaf(qq.w, kk.w, s0);
        }
        s0 *= scale;
        const int l0 = (t << 6) + ln;
        if (l0 > sp) s0 = -1e30f;

        float mt = s0;
#pragma unroll
        for (int o = 32; o; o >>= 1) mt = fmaxf(mt, __shfl_xor(mt, o));
        float mnew = fmaxf(m_run, mt);
        float f = __expf(m_run - mnew);
        float p0 = (l0 > sp) ? 0.f : __expf(s0 - mnew);
        m_run = mnew;
        dsum = dsum * f + p0;
        acc.x *= f; acc.y *= f; acc.z *= f; acc.w *= f;

        // phase B: lane owns dims lo*4..lo*4+3 for its half (hi) of rows
#pragma unroll
        for (int rr = 0; rr < 32; ++rr) {
            float4 vv = vt[hi * 32 + rr][lo];
            float pa = __shfl(p0, rr);        // v_readlane (uniform idx)
            float pb = __shfl(p0, rr + 32);
            float pr = hi ? pb : pa;
            acc.x = fmaf(pr, vv.x, acc.x);
            acc.y = fmaf(pr, vv.y, acc.y);
            acc.z = fmaf(pr, vv.z, acc.z);
            acc.w = fmaf(pr, vv.w, acc.w);
        }
    };

    stage(ktA, vtA, 0);
    __syncthreads();
    for (int t = 0; t < nt; t += 2) {
        if (t + 1 < nt) stage(ktB, vtB, t + 1);
        compute(ktA, vtA, t);
        __syncthreads();
        if (t + 1 < nt) {
            if (t + 2 < nt) stage(ktA, vtA, t + 2);
            compute(ktB, vtB, t + 1);
            __syncthreads();
        }
    }

    // combine row-halves and normalize
    acc.x += __shfl_xor(acc.x, 32);
    acc.y += __shfl_xor(acc.y, 32);
    acc.z += __shfl_xor(acc.z, 32);
    acc.w += __shfl_xor(acc.w, 32);
    float dd = dsum;
#pragma unroll
    for (int o = 32; o; o >>= 1) dd += __shfl_xor(dd, o);
    float inv = 1.f / dd;

    if (ln < 32) {
        float4 r = make_float4(acc.x * inv, acc.y * inv, acc.z * inv, acc.w * inv);
        *(float4*)(attn_out + ((size_t)b * NHEADS + kv * 8 + wv) * HD + lo * 4) = r;
    }
}

// ---------------------------------------------------------------------------
extern "C" void kernel_launch(void* const* d_in, const int* in_sizes, int n_in,
                              void* d_out, int out_size, void* d_ws, size_t ws_size,
                              hipStream_t stream) {
    const float* x   = (const float*)d_in[0];
    const float* wq  = (const float*)d_in[1];
    const float* wk  = (const float*)d_in[2];
    const float* wv  = (const float*)d_in[3];
    const float* wo  = (const float*)d_in[4];
    const float* rot = (const float*)d_in[5];
    const float* kc  = (const float*)d_in[6];
    const float* vc  = (const float*)d_in[7];
    const int*   sp  = (const int*)d_in[8];
    float* out = (float*)d_out;

    float* ws = (float*)d_ws;
    float* qkv_buf  = ws;                    // q 262144 | k 32768 | v 32768
    float* q_buf    = qkv_buf;
    float* k_buf    = qkv_buf + QSEC;
    float* v_buf    = qkv_buf + KSEC;
    float* qr_buf   = ws + 327680;           // 262144
    float* kr_buf   = ws + 589824;           // 32768
    float* attn_buf = ws + 622592;           // 262144
    float* P        = ws + 884736;           // 32 * 327680 partials

    // QKV projection (fused, k-split partials) + reduce
    gemm_fused<<<dim3(20, 32), 256, 0, stream>>>(x, wq, wk, wv, P, QKV_STRIDE);
    reduce_split<<<(QKV_STRIDE / 4 + 255) / 256, 256, 0, stream>>>(
        P, qkv_buf, QKV_STRIDE, QKV_STRIDE);

    // rotary on q and k
    rotary_all<<<(BATCH * NHEADS + BATCH * NKV) / RROWS, 128, 0, stream>>>(
        q_buf, k_buf, rot, qr_buf, kr_buf);

    // attention
    attn_decode<<<BATCH * NKV, 512, 0, stream>>>(qr_buf, kr_buf, v_buf, kc, vc, sp, attn_buf);

    // output projection (reuse P region) + reduce into d_out
    gemm_fused<<<dim3(16, 32), 256, 0, stream>>>(attn_buf, wo, wo, wo, P, QSEC);
    reduce_split<<<(QSEC / 4 + 255) / 256, 256, 0, stream>>>(P, out, QSEC, QSEC);
}

// Round 4
// 468.376 us; speedup vs baseline: 1.2525x; 1.2525x over previous
//
#include <hip/hip_runtime.h>
#include <hip/hip_bf16.h>

#define HIDDEN 8192
#define NHEADS 64
#define NKV 8
#define HD 128
#define BATCH 32
#define PADLEN 2048
#define NCHUNK 4
#define CHUNKLEN 512

// ---------------------------------------------------------------------------
// global_load_lds helper: DMA 16B/lane global->LDS. LDS dest = wave-uniform
// base + lane*16 (hardware-defined); global src is per-lane.
// ---------------------------------------------------------------------------
__device__ __forceinline__ void gld16(const float* g, float* l) {
    __builtin_amdgcn_global_load_lds(
        (const __attribute__((address_space(1))) void*)g,
        (__attribute__((address_space(3))) void*)l,
        16, 0, 0);
}

// readlane for float: bitcast, NOT value conversion (builtin is (uint,uint)!)
__device__ __forceinline__ float readlane_f(float v, int lane) {
    return __uint_as_float(__builtin_amdgcn_readlane(__float_as_uint(v), lane));
}

// ---------------------------------------------------------------------------
// Fused skinny GEMM: P[kb] += X[32][8192-chunk] @ {W0|W1|W2}.
// x is wave-uniform -> scalar s_load path (no LDS). No atomics: k-split
// partials to P, reduce_split sums them.
// ---------------------------------------------------------------------------
#define KC 256
#define QSEC 262144          // 32*8192
#define KSEC 294912          // QSEC + 32*1024
#define QKV_STRIDE 327680    // QSEC + 2*32*1024

__global__ __launch_bounds__(256) void gemm_fused(const float* __restrict__ X,
                                                  const float* __restrict__ W0,
                                                  const float* __restrict__ W1,
                                                  const float* __restrict__ W2,
                                                  float* __restrict__ P,
                                                  size_t pstride) {
    const int tid = threadIdx.x;
    const int cb = blockIdx.x, kb = blockIdx.y;
    const int k0 = kb * KC;

    const float* W;
    int N2, so, colbase;
    if (cb < 16)      { W = W0; N2 = 8192; so = 0;    colbase = cb * 512; }
    else if (cb < 18) { W = W1; N2 = 1024; so = QSEC; colbase = (cb - 16) * 512; }
    else              { W = W2; N2 = 1024; so = KSEC; colbase = (cb - 18) * 512; }

    const int c0 = colbase + tid * 2;
    float2 acc[BATCH];
#pragma unroll
    for (int b = 0; b < BATCH; ++b) acc[b] = make_float2(0.f, 0.f);

    const float* wp = W + (size_t)k0 * N2 + c0;
    for (int kk = 0; kk < KC; kk += 4) {
        float2 w0 = *(const float2*)(wp);
        float2 w1 = *(const float2*)(wp + N2);
        float2 w2 = *(const float2*)(wp + 2 * (size_t)N2);
        float2 w3 = *(const float2*)(wp + 3 * (size_t)N2);
        wp += 4 * (size_t)N2;
        const float* xk = X + k0 + kk;
#pragma unroll
        for (int b = 0; b < BATCH; ++b) {
            float4 xv = *(const float4*)(xk + (size_t)b * HIDDEN);  // uniform -> s_load
            acc[b].x = fmaf(xv.x, w0.x, acc[b].x);
            acc[b].y = fmaf(xv.x, w0.y, acc[b].y);
            acc[b].x = fmaf(xv.y, w1.x, acc[b].x);
            acc[b].y = fmaf(xv.y, w1.y, acc[b].y);
            acc[b].x = fmaf(xv.z, w2.x, acc[b].x);
            acc[b].y = fmaf(xv.z, w2.y, acc[b].y);
            acc[b].x = fmaf(xv.w, w3.x, acc[b].x);
            acc[b].y = fmaf(xv.w, w3.y, acc[b].y);
        }
    }
    float* pdst = P + (size_t)kb * pstride + so + c0;
#pragma unroll
    for (int b = 0; b < BATCH; ++b)
        *(float2*)(pdst + (size_t)b * N2) = acc[b];
}

// out[i] = sum_s P[s][i]
__global__ __launch_bounds__(256) void reduce_split(const float* __restrict__ P,
                                                    float* __restrict__ out,
                                                    int nelem, size_t pstride) {
    int i = (blockIdx.x * 256 + threadIdx.x) * 4;
    if (i >= nelem) return;
    float4 a = *(const float4*)(P + i);
#pragma unroll 4
    for (int s = 1; s < 32; ++s) {
        float4 b = *(const float4*)(P + (size_t)s * pstride + i);
        a.x += b.x; a.y += b.y; a.z += b.z; a.w += b.w;
    }
    *(float4*)(out + i) = a;
}

// ---------------------------------------------------------------------------
// Rotary: rows 0..2047 = q rows (32*64), rows 2048..2303 = k rows (32*8).
// ---------------------------------------------------------------------------
#define RROWS 16
__global__ __launch_bounds__(128) void rotary_all(const float* __restrict__ qin,
                                                  const float* __restrict__ kin,
                                                  const float* __restrict__ rot,
                                                  float* __restrict__ qout,
                                                  float* __restrict__ kout) {
    __shared__ float rows[RROWS][HD];
    const int tid = threadIdx.x;
    const int row0 = blockIdx.x * RROWS;

    for (int i = tid; i < RROWS * (HD / 4); i += 128) {
        int r = i >> 5;
        int d4 = i & 31;
        int gr = row0 + r;
        const float* src = (gr < BATCH * NHEADS)
                               ? (qin + (size_t)gr * HD)
                               : (kin + (size_t)(gr - BATCH * NHEADS) * HD);
        *(float4*)&rows[r][d4 * 4] = *(const float4*)(src + d4 * 4);
    }
    __syncthreads();

    float acc[RROWS];
#pragma unroll
    for (int r = 0; r < RROWS; ++r) acc[r] = 0.f;

    for (int d4 = 0; d4 < HD; d4 += 4) {
        float r0 = rot[(size_t)(d4 + 0) * HD + tid];
        float r1 = rot[(size_t)(d4 + 1) * HD + tid];
        float r2 = rot[(size_t)(d4 + 2) * HD + tid];
        float r3 = rot[(size_t)(d4 + 3) * HD + tid];
#pragma unroll
        for (int r = 0; r < RROWS; ++r) {
            float4 xv = *(const float4*)&rows[r][d4];
            acc[r] = fmaf(xv.x, r0, acc[r]);
            acc[r] = fmaf(xv.y, r1, acc[r]);
            acc[r] = fmaf(xv.z, r2, acc[r]);
            acc[r] = fmaf(xv.w, r3, acc[r]);
        }
    }
#pragma unroll
    for (int r = 0; r < RROWS; ++r) {
        int gr = row0 + r;
        float* dst = (gr < BATCH * NHEADS)
                         ? (qout + (size_t)gr * HD)
                         : (kout + (size_t)(gr - BATCH * NHEADS) * HD);
        dst[tid] = acc[r];
    }
}

// ---------------------------------------------------------------------------
// Flash-decode attention, split-KV x4.
// Grid: 1024 = (chunk, b, kv); block 512 thr = 8 waves; wave = one q-head.
// Chunk = 512 positions = 16 tiles of 32 rows. TILE=32 double-buffered
// (64 KB LDS -> 2 blocks/CU; VGPR<=128 via half-q-per-lane).
// Lane: lo = row (0..31), hi = dim-half (q dims hi*64..hi*64+63).
// Writes unnormalized (m, d, acc) partials; attn_combine merges chunks.
// ---------------------------------------------------------------------------
#define TILE 32
__global__ __launch_bounds__(512, 4) void attn_decode(
        const float* __restrict__ qr, const float* __restrict__ kr,
        const float* __restrict__ vnew, const float* __restrict__ kcache,
        const float* __restrict__ vcache, const int* __restrict__ sp_ptr,
        float* __restrict__ part_acc, float* __restrict__ part_md) {
    __shared__ float4 ktA[TILE][32], vtA[TILE][32];
    __shared__ float4 ktB[TILE][32], vtB[TILE][32];

    const int tid = threadIdx.x;
    const int wv = tid >> 6, ln = tid & 63;
    const int lo = ln & 31, hi = ln >> 5;
    const int chunk = blockIdx.x >> 8;
    const int b  = (blockIdx.x >> 3) & 31;
    const int kv = blockIdx.x & 7;
    const int chunk0 = chunk * CHUNKLEN;
    const int sp = sp_ptr[0];
    const float scale = 0.08838834764831845f;  // 1/sqrt(128)
    const int bh = b * NHEADS + kv * 8 + wv;

    const float* kbase = kcache + (size_t)(b * NKV + kv) * PADLEN * HD;
    const float* vbase = vcache + (size_t)(b * NKV + kv) * PADLEN * HD;
    const float* knew  = kr   + (size_t)(b * NKV + kv) * HD;
    const float* vnw   = vnew + (size_t)(b * NKV + kv) * HD;

    // this wave's head q, lane-half split: hi=0 dims 0..63, hi=1 dims 64..127
    float4 qreg[16];
    {
        const float4* qsrc = (const float4*)(qr + (size_t)bh * HD) + hi * 16;
#pragma unroll
        for (int i = 0; i < 16; ++i) qreg[i] = qsrc[i];
    }

    float m_run = -1e30f, dsum = 0.f;
    float4 acc = make_float4(0.f, 0.f, 0.f, 0.f);

    int valid = sp + 1 - chunk0;                       // positions in this chunk
    int nt = valid <= 0 ? 0 : (valid + TILE - 1) >> 5;
    if (nt > CHUNKLEN / TILE) nt = CHUNKLEN / TILE;

    auto stage = [&](float4 (*kt)[32], float4 (*vt)[32], int t) {
        const int tile0 = chunk0 + (t << 5);
#pragma unroll
        for (int i = 0; i < 2; ++i) {
            int sbase = (i * 8 + wv) << 6;   // wave-uniform slot base (K: 1024 slots)
            int s = sbase + ln;
            int r = s >> 5, j = s & 31;      // r: 0..31 row, j: slot in row
            int gl = tile0 + r;
            const float* krow = (gl == sp) ? knew : (kbase + (size_t)gl * HD);
            const float* vrow = (gl == sp) ? vnw  : (vbase + (size_t)gl * HD);
            // K pre-swizzled at global source -> linear DMA lands swizzled
            gld16(krow + ((j ^ r) << 2), (float*)kt + (size_t)sbase * 4);
            gld16(vrow + (j << 2),       (float*)vt + (size_t)sbase * 4);
        }
    };

    auto compute = [&](float4 (*kt)[32], float4 (*vt)[32], int t) {
        // phase A: lane (lo,hi) computes half-dot of row lo
        float sh = 0.f;
#pragma unroll
        for (int j = 0; j < 16; ++j) {
            float4 kk = kt[lo][(hi * 16 + j) ^ lo];
            float4 qq = qreg[j];
            sh = fmaf(qq.x, kk.x, sh);
            sh = fmaf(qq.y, kk.y, sh);
            sh = fmaf(qq.z, kk.z, sh);
            sh = fmaf(qq.w, kk.w, sh);
        }
        float s0 = (sh + __shfl_xor(sh, 32)) * scale;   // full dot, dup in halves
        const int l0 = chunk0 + (t << 5) + lo;
        const bool dead = l0 > sp;
        if (dead) s0 = -1e30f;

        float mt = s0;
#pragma unroll
        for (int o = 16; o; o >>= 1) mt = fmaxf(mt, __shfl_xor(mt, o));
        float mnew = fmaxf(m_run, mt);
        float f = __expf(m_run - mnew);
        float p0 = dead ? 0.f : __expf(s0 - mnew);
        m_run = mnew;
        dsum = dsum * f + p0;
        acc.x *= f; acc.y *= f; acc.z *= f; acc.w *= f;

        // phase B: lane owns dims lo*4..lo*4+3, hi half of rows
#pragma unroll
        for (int i = 0; i < 16; ++i) {
            float4 vv = vt[hi * 16 + i][lo];
            float pa = readlane_f(p0, i);        // row i (bitcast readlane!)
            float pb = readlane_f(p0, 16 + i);   // row 16+i
            float pr = hi ? pb : pa;
            acc.x = fmaf(pr, vv.x, acc.x);
            acc.y = fmaf(pr, vv.y, acc.y);
            acc.z = fmaf(pr, vv.z, acc.z);
            acc.w = fmaf(pr, vv.w, acc.w);
        }
    };

    if (nt > 0) {
        stage(ktA, vtA, 0);
        __syncthreads();
        for (int t = 0; t < nt; t += 2) {
            if (t + 1 < nt) stage(ktB, vtB, t + 1);
            compute(ktA, vtA, t);
            __syncthreads();
            if (t + 1 < nt) {
                if (t + 2 < nt) stage(ktA, vtA, t + 2);
                compute(ktB, vtB, t + 1);
                __syncthreads();
            }
        }
    }

    // combine row-halves; write unnormalized partials
    acc.x += __shfl_xor(acc.x, 32);
    acc.y += __shfl_xor(acc.y, 32);
    acc.z += __shfl_xor(acc.z, 32);
    acc.w += __shfl_xor(acc.w, 32);
    float dd = dsum;
#pragma unroll
    for (int o = 16; o; o >>= 1) dd += __shfl_xor(dd, o);

    if (hi == 0)
        *(float4*)(part_acc + ((size_t)chunk * (BATCH * NHEADS) + bh) * HD + lo * 4) = acc;
    if (ln == 0) {
        float2 md = make_float2(m_run, dd);
        *(float2*)(part_md + ((size_t)chunk * (BATCH * NHEADS) + bh) * 2) = md;
    }
}

// merge the NCHUNK split-KV partials per head
__global__ __launch_bounds__(128) void attn_combine(const float* __restrict__ part_acc,
                                                    const float* __restrict__ part_md,
                                                    float* __restrict__ attn_out) {
    const int bh = blockIdx.x;
    const int d = threadIdx.x;
    float m[NCHUNK], dd[NCHUNK];
    float M = -1e30f;
#pragma unroll
    for (int c = 0; c < NCHUNK; ++c) {
        m[c]  = part_md[((size_t)c * (BATCH * NHEADS) + bh) * 2];
        dd[c] = part_md[((size_t)c * (BATCH * NHEADS) + bh) * 2 + 1];
        M = fmaxf(M, m[c]);
    }
    float D = 0.f, o = 0.f;
#pragma unroll
    for (int c = 0; c < NCHUNK; ++c) {
        float w = __expf(m[c] - M);
        D += dd[c] * w;
        o += part_acc[((size_t)c * (BATCH * NHEADS) + bh) * HD + d] * w;
    }
    attn_out[(size_t)bh * HD + d] = o / D;
}

// ---------------------------------------------------------------------------
extern "C" void kernel_launch(void* const* d_in, const int* in_sizes, int n_in,
                              void* d_out, int out_size, void* d_ws, size_t ws_size,
                              hipStream_t stream) {
    const float* x   = (const float*)d_in[0];
    const float* wq  = (const float*)d_in[1];
    const float* wk  = (const float*)d_in[2];
    const float* wv  = (const float*)d_in[3];
    const float* wo  = (const float*)d_in[4];
    const float* rot = (const float*)d_in[5];
    const float* kc  = (const float*)d_in[6];
    const float* vc  = (const float*)d_in[7];
    const int*   sp  = (const int*)d_in[8];
    float* out = (float*)d_out;

    float* ws = (float*)d_ws;
    float* qkv_buf  = ws;                    // q 262144 | k 32768 | v 32768
    float* q_buf    = qkv_buf;
    float* k_buf    = qkv_buf + QSEC;
    float* v_buf    = qkv_buf + KSEC;
    float* qr_buf   = ws + 327680;           // 262144
    float* kr_buf   = ws + 589824;           // 32768
    float* attn_buf = ws + 622592;           // 262144
    float* P        = ws + 884736;           // 32 * 327680 qkv partials (reused)
    // split-KV partials overlay the (already consumed) P region during attn
    float* part_acc = P;                     // 4*2048*128 = 1048576
    float* part_md  = P + 1048576;           // 4*2048*2   = 16384

    // QKV projection (fused, k-split partials) + reduce
    gemm_fused<<<dim3(20, 32), 256, 0, stream>>>(x, wq, wk, wv, P, QKV_STRIDE);
    reduce_split<<<(QKV_STRIDE / 4 + 255) / 256, 256, 0, stream>>>(
        P, qkv_buf, QKV_STRIDE, QKV_STRIDE);

    // rotary on q and k
    rotary_all<<<(BATCH * NHEADS + BATCH * NKV) / RROWS, 128, 0, stream>>>(
        q_buf, k_buf, rot, qr_buf, kr_buf);

    // attention (split-KV) + combine
    attn_decode<<<NCHUNK * BATCH * NKV, 512, 0, stream>>>(
        qr_buf, kr_buf, v_buf, kc, vc, sp, part_acc, part_md);
    attn_combine<<<BATCH * NHEADS, 128, 0, stream>>>(part_acc, part_md, attn_buf);

    // output projection (reuse P region) + reduce into d_out
    gemm_fused<<<dim3(16, 32), 256, 0, stream>>>(attn_buf, wo, wo, wo, P, QSEC);
    reduce_split<<<(QSEC / 4 + 255) / 256, 256, 0, stream>>>(P, out, QSEC, QSEC);
}

// Round 5
// 384.904 us; speedup vs baseline: 1.5241x; 1.2169x over previous
//
#include <hip/hip_runtime.h>
#include <hip/hip_bf16.h>

#define HIDDEN 8192
#define NHEADS 64
#define NKV 8
#define HD 128
#define BATCH 32
#define PADLEN 2048
#define NCHUNK 4
#define CHUNKLEN 512

// ---------------------------------------------------------------------------
// global_load_lds helper: DMA 16B/lane global->LDS. LDS dest = wave-uniform
// base + lane*16 (hardware-defined); global src is per-lane.
// ---------------------------------------------------------------------------
__device__ __forceinline__ void gld16(const float* g, float* l) {
    __builtin_amdgcn_global_load_lds(
        (const __attribute__((address_space(1))) void*)g,
        (__attribute__((address_space(3))) void*)l,
        16, 0, 0);
}

// readlane for float: bitcast, NOT value conversion (builtin is (uint,uint)!)
__device__ __forceinline__ float readlane_f(float v, int lane) {
    return __uint_as_float(__builtin_amdgcn_readlane(__float_as_uint(v), lane));
}

// ---------------------------------------------------------------------------
// Fused skinny GEMM: P[kb] += X[32][8192-chunk] @ {W0|W1|W2}.
// x is wave-uniform -> scalar s_load path (no LDS). No atomics: k-split
// partials to P, reduce_split sums them.
// ---------------------------------------------------------------------------
#define KC 256
#define QSEC 262144          // 32*8192
#define KSEC 294912          // QSEC + 32*1024
#define QKV_STRIDE 327680    // QSEC + 2*32*1024

__global__ __launch_bounds__(256) void gemm_fused(const float* __restrict__ X,
                                                  const float* __restrict__ W0,
                                                  const float* __restrict__ W1,
                                                  const float* __restrict__ W2,
                                                  float* __restrict__ P,
                                                  size_t pstride) {
    const int tid = threadIdx.x;
    const int cb = blockIdx.x, kb = blockIdx.y;
    const int k0 = kb * KC;

    const float* W;
    int N2, so, colbase;
    if (cb < 16)      { W = W0; N2 = 8192; so = 0;    colbase = cb * 512; }
    else if (cb < 18) { W = W1; N2 = 1024; so = QSEC; colbase = (cb - 16) * 512; }
    else              { W = W2; N2 = 1024; so = KSEC; colbase = (cb - 18) * 512; }

    const int c0 = colbase + tid * 2;
    float2 acc[BATCH];
#pragma unroll
    for (int b = 0; b < BATCH; ++b) acc[b] = make_float2(0.f, 0.f);

    const float* wp = W + (size_t)k0 * N2 + c0;
    for (int kk = 0; kk < KC; kk += 4) {
        float2 w0 = *(const float2*)(wp);
        float2 w1 = *(const float2*)(wp + N2);
        float2 w2 = *(const float2*)(wp + 2 * (size_t)N2);
        float2 w3 = *(const float2*)(wp + 3 * (size_t)N2);
        wp += 4 * (size_t)N2;
        const float* xk = X + k0 + kk;
#pragma unroll
        for (int b = 0; b < BATCH; ++b) {
            float4 xv = *(const float4*)(xk + (size_t)b * HIDDEN);  // uniform -> s_load
            acc[b].x = fmaf(xv.x, w0.x, acc[b].x);
            acc[b].y = fmaf(xv.x, w0.y, acc[b].y);
            acc[b].x = fmaf(xv.y, w1.x, acc[b].x);
            acc[b].y = fmaf(xv.y, w1.y, acc[b].y);
            acc[b].x = fmaf(xv.z, w2.x, acc[b].x);
            acc[b].y = fmaf(xv.z, w2.y, acc[b].y);
            acc[b].x = fmaf(xv.w, w3.x, acc[b].x);
            acc[b].y = fmaf(xv.w, w3.y, acc[b].y);
        }
    }
    float* pdst = P + (size_t)kb * pstride + so + c0;
#pragma unroll
    for (int b = 0; b < BATCH; ++b)
        *(float2*)(pdst + (size_t)b * N2) = acc[b];
}

// out[i] = sum_s P[s][i]
__global__ __launch_bounds__(256) void reduce_split(const float* __restrict__ P,
                                                    float* __restrict__ out,
                                                    int nelem, size_t pstride) {
    int i = (blockIdx.x * 256 + threadIdx.x) * 4;
    if (i >= nelem) return;
    float4 a = *(const float4*)(P + i);
#pragma unroll 4
    for (int s = 1; s < 32; ++s) {
        float4 b = *(const float4*)(P + (size_t)s * pstride + i);
        a.x += b.x; a.y += b.y; a.z += b.z; a.w += b.w;
    }
    *(float4*)(out + i) = a;
}

// ---------------------------------------------------------------------------
// Rotary: rows 0..2047 = q rows (32*64), rows 2048..2303 = k rows (32*8).
// ---------------------------------------------------------------------------
#define RROWS 16
__global__ __launch_bounds__(128) void rotary_all(const float* __restrict__ qin,
                                                  const float* __restrict__ kin,
                                                  const float* __restrict__ rot,
                                                  float* __restrict__ qout,
                                                  float* __restrict__ kout) {
    __shared__ float rows[RROWS][HD];
    const int tid = threadIdx.x;
    const int row0 = blockIdx.x * RROWS;

    for (int i = tid; i < RROWS * (HD / 4); i += 128) {
        int r = i >> 5;
        int d4 = i & 31;
        int gr = row0 + r;
        const float* src = (gr < BATCH * NHEADS)
                               ? (qin + (size_t)gr * HD)
                               : (kin + (size_t)(gr - BATCH * NHEADS) * HD);
        *(float4*)&rows[r][d4 * 4] = *(const float4*)(src + d4 * 4);
    }
    __syncthreads();

    float acc[RROWS];
#pragma unroll
    for (int r = 0; r < RROWS; ++r) acc[r] = 0.f;

    for (int d4 = 0; d4 < HD; d4 += 4) {
        float r0 = rot[(size_t)(d4 + 0) * HD + tid];
        float r1 = rot[(size_t)(d4 + 1) * HD + tid];
        float r2 = rot[(size_t)(d4 + 2) * HD + tid];
        float r3 = rot[(size_t)(d4 + 3) * HD + tid];
#pragma unroll
        for (int r = 0; r < RROWS; ++r) {
            float4 xv = *(const float4*)&rows[r][d4];
            acc[r] = fmaf(xv.x, r0, acc[r]);
            acc[r] = fmaf(xv.y, r1, acc[r]);
            acc[r] = fmaf(xv.z, r2, acc[r]);
            acc[r] = fmaf(xv.w, r3, acc[r]);
        }
    }
#pragma unroll
    for (int r = 0; r < RROWS; ++r) {
        int gr = row0 + r;
        float* dst = (gr < BATCH * NHEADS)
                         ? (qout + (size_t)gr * HD)
                         : (kout + (size_t)(gr - BATCH * NHEADS) * HD);
        dst[tid] = acc[r];
    }
}

// ---------------------------------------------------------------------------
// Flash-decode attention, split-KV x4, counted-vmcnt ring pipeline (T4).
// Grid: 1024 = (chunk, b, kv); block 512 thr = 8 waves; wave = one q-head.
// TILE=16 rows, ring of 4 buffers (64 KB LDS -> 2 blocks/CU), prefetch
// depth 2. Exactly 2 gld16 per wave per tile -> s_waitcnt vmcnt(4) before the
// raw s_barrier keeps the 2 newest tiles' loads in flight (no vmcnt(0) drain).
// Tail stays count-uniform via clamped dummy stages into dead ring slots.
// Lane mapping: phase A lane=(row=ln&15, quarter=ln>>4); phase B
// lane=(dslot=ln&31, half=ln>>5). K swizzled j^(r&7) via pre-swizzled source.
// ---------------------------------------------------------------------------
#define TILE 16
#define NBUF 4
__global__ __launch_bounds__(512, 4) void attn_decode(
        const float* __restrict__ qr, const float* __restrict__ kr,
        const float* __restrict__ vnew, const float* __restrict__ kcache,
        const float* __restrict__ vcache, const int* __restrict__ sp_ptr,
        float* __restrict__ part_acc, float* __restrict__ part_md) {
    __shared__ float4 kt[NBUF][TILE][32];
    __shared__ float4 vt[NBUF][TILE][32];

    const int tid = threadIdx.x;
    const int wv = tid >> 6, ln = tid & 63;
    const int row = ln & 15, qd = ln >> 4;      // phase A geometry
    const int dslot = ln & 31, hh = ln >> 5;    // phase B geometry
    const int chunk = blockIdx.x >> 8;
    const int b  = (blockIdx.x >> 3) & 31;
    const int kv = blockIdx.x & 7;
    const int chunk0 = chunk * CHUNKLEN;
    const int sp = sp_ptr[0];
    const float scale = 0.08838834764831845f;   // 1/sqrt(128)
    const int bh = b * NHEADS + kv * 8 + wv;

    const float* kbase = kcache + (size_t)(b * NKV + kv) * PADLEN * HD;
    const float* vbase = vcache + (size_t)(b * NKV + kv) * PADLEN * HD;
    const float* knew  = kr   + (size_t)(b * NKV + kv) * HD;
    const float* vnw   = vnew + (size_t)(b * NKV + kv) * HD;

    // this wave's head q, quarter per lane: dims qd*32 .. qd*32+31
    float4 qreg[8];
    {
        const float4* qsrc = (const float4*)(qr + (size_t)bh * HD) + qd * 8;
#pragma unroll
        for (int i = 0; i < 8; ++i) qreg[i] = qsrc[i];
    }

    // staging geometry: this lane stages row sr, physical slot sj
    const int sr  = wv * 2 + (ln >> 5);    // 0..15
    const int sj  = ln & 31;
    const int sjk = sj ^ (sr & 7);         // logical K slot (pre-swizzled src)

    float m_run = -1e30f, dsum = 0.f;
    float4 acc = make_float4(0.f, 0.f, 0.f, 0.f);

    int valid = sp + 1 - chunk0;
    int nt = valid <= 0 ? 0 : (valid + TILE - 1) >> 4;
    if (nt > CHUNKLEN / TILE) nt = CHUNKLEN / TILE;

    auto stage = [&](int ts, int slot) {
        const int gl = chunk0 + (ts << 4) + sr;
        const float* krow = (gl == sp) ? knew : (kbase + (size_t)gl * HD);
        const float* vrow = (gl == sp) ? vnw  : (vbase + (size_t)gl * HD);
        gld16(krow + (sjk << 2), (float*)&kt[slot][0][0] + wv * 256);
        gld16(vrow + (sj  << 2), (float*)&vt[slot][0][0] + wv * 256);
    };

    auto compute = [&](int t) {
        const float4 (*kt_)[32] = kt[t & 3];
        const float4 (*vt_)[32] = vt[t & 3];
        // phase A: quarter-dot of row `row`, dims qd*32..qd*32+31
        float sh = 0.f;
#pragma unroll
        for (int jj = 0; jj < 8; ++jj) {
            float4 kk = kt_[row][(qd * 8 + jj) ^ (row & 7)];
            float4 qq = qreg[jj];
            sh = fmaf(qq.x, kk.x, sh);
            sh = fmaf(qq.y, kk.y, sh);
            sh = fmaf(qq.z, kk.z, sh);
            sh = fmaf(qq.w, kk.w, sh);
        }
        sh += __shfl_xor(sh, 16);
        sh += __shfl_xor(sh, 32);
        float s0 = sh * scale;
        const int l0 = chunk0 + (t << 4) + row;
        const bool dead = l0 > sp;
        if (dead) s0 = -1e30f;

        float mt = s0;
        mt = fmaxf(mt, __shfl_xor(mt, 1));
        mt = fmaxf(mt, __shfl_xor(mt, 2));
        mt = fmaxf(mt, __shfl_xor(mt, 4));
        mt = fmaxf(mt, __shfl_xor(mt, 8));
        float mnew = fmaxf(m_run, mt);
        float f = __expf(m_run - mnew);
        float p0 = dead ? 0.f : __expf(s0 - mnew);
        m_run = mnew;
        dsum = dsum * f + p0;               // per-lane; reduced over 16-group at end
        acc.x *= f; acc.y *= f; acc.z *= f; acc.w *= f;

        // phase B: lane owns dims dslot*4..+3, rows hh*8..hh*8+7
#pragma unroll
        for (int i = 0; i < 8; ++i) {
            float4 vv = vt_[hh * 8 + i][dslot];
            float pa = readlane_f(p0, i);
            float pb = readlane_f(p0, 8 + i);
            float pr = hh ? pb : pa;
            acc.x = fmaf(pr, vv.x, acc.x);
            acc.y = fmaf(pr, vv.y, acc.y);
            acc.z = fmaf(pr, vv.z, acc.z);
            acc.w = fmaf(pr, vv.w, acc.w);
        }
    };

    if (nt > 0) {
        stage(0, 0);
        stage(nt > 1 ? 1 : 0, 1);
        for (int t = 0; t < nt; ++t) {
            int ts = t + 2 < nt ? t + 2 : nt - 1;    // clamped dummy keeps counts uniform
            stage(ts, (t + 2) & 3);
            asm volatile("s_waitcnt vmcnt(4)" ::: "memory");  // tile t complete; t+1,t+2 in flight
            __builtin_amdgcn_s_barrier();
            compute(t);
        }
    }

    // combine row-halves; reduce denominator over the 16-lane row group
    acc.x += __shfl_xor(acc.x, 32);
    acc.y += __shfl_xor(acc.y, 32);
    acc.z += __shfl_xor(acc.z, 32);
    acc.w += __shfl_xor(acc.w, 32);
    float dd = dsum;
    dd += __shfl_xor(dd, 1);
    dd += __shfl_xor(dd, 2);
    dd += __shfl_xor(dd, 4);
    dd += __shfl_xor(dd, 8);

    if (hh == 0)
        *(float4*)(part_acc + ((size_t)chunk * (BATCH * NHEADS) + bh) * HD + dslot * 4) = acc;
    if (ln == 0) {
        float2 md = make_float2(m_run, dd);
        *(float2*)(part_md + ((size_t)chunk * (BATCH * NHEADS) + bh) * 2) = md;
    }
}

// merge the NCHUNK split-KV partials per head
__global__ __launch_bounds__(128) void attn_combine(const float* __restrict__ part_acc,
                                                    const float* __restrict__ part_md,
                                                    float* __restrict__ attn_out) {
    const int bh = blockIdx.x;
    const int d = threadIdx.x;
    float m[NCHUNK], dd[NCHUNK];
    float M = -1e30f;
#pragma unroll
    for (int c = 0; c < NCHUNK; ++c) {
        m[c]  = part_md[((size_t)c * (BATCH * NHEADS) + bh) * 2];
        dd[c] = part_md[((size_t)c * (BATCH * NHEADS) + bh) * 2 + 1];
        M = fmaxf(M, m[c]);
    }
    float D = 0.f, o = 0.f;
#pragma unroll
    for (int c = 0; c < NCHUNK; ++c) {
        float w = __expf(m[c] - M);
        D += dd[c] * w;
        o += part_acc[((size_t)c * (BATCH * NHEADS) + bh) * HD + d] * w;
    }
    attn_out[(size_t)bh * HD + d] = o / D;
}

// ---------------------------------------------------------------------------
extern "C" void kernel_launch(void* const* d_in, const int* in_sizes, int n_in,
                              void* d_out, int out_size, void* d_ws, size_t ws_size,
                              hipStream_t stream) {
    const float* x   = (const float*)d_in[0];
    const float* wq  = (const float*)d_in[1];
    const float* wk  = (const float*)d_in[2];
    const float* wv  = (const float*)d_in[3];
    const float* wo  = (const float*)d_in[4];
    const float* rot = (const float*)d_in[5];
    const float* kc  = (const float*)d_in[6];
    const float* vc  = (const float*)d_in[7];
    const int*   sp  = (const int*)d_in[8];
    float* out = (float*)d_out;

    float* ws = (float*)d_ws;
    float* qkv_buf  = ws;                    // q 262144 | k 32768 | v 32768
    float* q_buf    = qkv_buf;
    float* k_buf    = qkv_buf + QSEC;
    float* v_buf    = qkv_buf + KSEC;
    float* qr_buf   = ws + 327680;           // 262144
    float* kr_buf   = ws + 589824;           // 32768
    float* attn_buf = ws + 622592;           // 262144
    float* P        = ws + 884736;           // 32 * 327680 qkv partials (reused)
    // split-KV partials overlay the (already consumed) P region during attn
    float* part_acc = P;                     // 4*2048*128 = 1048576
    float* part_md  = P + 1048576;           // 4*2048*2   = 16384

    // QKV projection (fused, k-split partials) + reduce
    gemm_fused<<<dim3(20, 32), 256, 0, stream>>>(x, wq, wk, wv, P, QKV_STRIDE);
    reduce_split<<<(QKV_STRIDE / 4 + 255) / 256, 256, 0, stream>>>(
        P, qkv_buf, QKV_STRIDE, QKV_STRIDE);

    // rotary on q and k
    rotary_all<<<(BATCH * NHEADS + BATCH * NKV) / RROWS, 128, 0, stream>>>(
        q_buf, k_buf, rot, qr_buf, kr_buf);

    // attention (split-KV) + combine
    attn_decode<<<NCHUNK * BATCH * NKV, 512, 0, stream>>>(
        qr_buf, kr_buf, v_buf, kc, vc, sp, part_acc, part_md);
    attn_combine<<<BATCH * NHEADS, 128, 0, stream>>>(part_acc, part_md, attn_buf);

    // output projection (reuse P region) + reduce into d_out
    gemm_fused<<<dim3(16, 32), 256, 0, stream>>>(attn_buf, wo, wo, wo, P, QSEC);
    reduce_split<<<(QSEC / 4 + 255) / 256, 256, 0, stream>>>(P, out, QSEC, QSEC);
}

// Round 6
// 303.323 us; speedup vs baseline: 1.9340x; 1.2690x over previous
//
#include <hip/hip_runtime.h>
#include <hip/hip_bf16.h>

#define HIDDEN 8192
#define NHEADS 64
#define NKV 8
#define HD 128
#define BATCH 32
#define PADLEN 2048
#define NCHUNK 4
#define CHUNKLEN 512

using bf16x8 = __attribute__((ext_vector_type(8))) short;
using f32x4 = __attribute__((ext_vector_type(4))) float;

// ---------------------------------------------------------------------------
// helpers
// ---------------------------------------------------------------------------
__device__ __forceinline__ void gld16(const float* g, float* l) {
    __builtin_amdgcn_global_load_lds(
        (const __attribute__((address_space(1))) void*)g,
        (__attribute__((address_space(3))) void*)l,
        16, 0, 0);
}

// readlane for float: bitcast, NOT value conversion (builtin is (uint,uint)!)
__device__ __forceinline__ float readlane_f(float v, int lane) {
    return __uint_as_float(__builtin_amdgcn_readlane(__float_as_uint(v), lane));
}

__device__ __forceinline__ short f2bf(float f) {      // RNE f32->bf16
    unsigned u = __float_as_uint(f);
    u += 0x7fff + ((u >> 16) & 1);
    return (short)(u >> 16);
}
__device__ __forceinline__ float bf2f(short s) {
    return __uint_as_float(((unsigned)(unsigned short)s) << 16);
}

// ---------------------------------------------------------------------------
// split a f32 vector into hi/lo bf16 (x = hi + lo, residual ~2^-17 rel)
// ---------------------------------------------------------------------------
__global__ __launch_bounds__(256) void cvt_split(const float* __restrict__ in,
                                                 short* __restrict__ hi,
                                                 short* __restrict__ lo, int n4) {
    int i = blockIdx.x * 256 + threadIdx.x;
    if (i >= n4) return;
    float4 v = ((const float4*)in)[i];
    short4 h, l;
    h.x = f2bf(v.x); l.x = f2bf(v.x - bf2f(h.x));
    h.y = f2bf(v.y); l.y = f2bf(v.y - bf2f(h.y));
    h.z = f2bf(v.z); l.z = f2bf(v.z - bf2f(h.z));
    h.w = f2bf(v.w); l.w = f2bf(v.w - bf2f(h.w));
    ((short4*)hi)[i] = h;
    ((short4*)lo)[i] = l;
}

// ---------------------------------------------------------------------------
// MFMA split-bf16 skinny GEMM: P[kb] = X[32][K-slice] @ {W0|W1|W2}.
// X pre-split into bf16 hi/lo; W streamed f32 and split in-register.
// 3 MFMA passes: xh*wh + xl*wh + xh*wl (~f32 accuracy, f32 accumulate).
// mfma_f32_16x16x32_bf16 fragments: A lane row=l&15, k=(l>>4)*8+j;
// B lane col=l&15, k=(l>>4)*8+j; C/D col=l&15, row=(l>>4)*4+reg (m89).
// Block 256 thr = 4 waves; wave covers 64 cols (4 n-tiles); no LDS.
// k-split via blockIdx.y -> partials in P, reduce_split sums.
// ---------------------------------------------------------------------------
#define KC 256
#define QSEC 262144          // 32*8192
#define KSEC 294912          // QSEC + 32*1024
#define QKV_STRIDE 327680    // QSEC + 2*32*1024
#define NSPLIT 16
#define KSLICE 512           // HIDDEN / NSPLIT

__global__ __launch_bounds__(256) void gemm_mfma(
        const short* __restrict__ xhi, const short* __restrict__ xlo,
        const float* __restrict__ W0, const float* __restrict__ W1,
        const float* __restrict__ W2, float* __restrict__ P, size_t pstride) {
    const int tid = threadIdx.x;
    const int wv = tid >> 6, ln = tid & 63;
    const int cb = blockIdx.x, kb = blockIdx.y;

    const float* W; int N2; size_t so; int nbase;
    if (cb < 32)      { W = W0; N2 = 8192; so = 0;    nbase = cb * 256; }
    else if (cb < 36) { W = W1; N2 = 1024; so = QSEC; nbase = (cb - 32) * 256; }
    else              { W = W2; N2 = 1024; so = KSEC; nbase = (cb - 36) * 256; }

    const int n0 = nbase + wv * 64;      // this wave: cols n0..n0+63
    const int lrow = ln & 15;
    const int kgrp = ln >> 4;

    f32x4 acc[2][4];
#pragma unroll
    for (int mt = 0; mt < 2; ++mt)
#pragma unroll
        for (int nt = 0; nt < 4; ++nt)
            acc[mt][nt] = (f32x4){0.f, 0.f, 0.f, 0.f};

    const int k0 = kb * KSLICE;
    for (int kk = 0; kk < KSLICE; kk += 32) {
        const int kbase = k0 + kk + kgrp * 8;
        bf16x8 a0h = *(const bf16x8*)(xhi + (size_t)lrow * HIDDEN + kbase);
        bf16x8 a0l = *(const bf16x8*)(xlo + (size_t)lrow * HIDDEN + kbase);
        bf16x8 a1h = *(const bf16x8*)(xhi + (size_t)(lrow + 16) * HIDDEN + kbase);
        bf16x8 a1l = *(const bf16x8*)(xlo + (size_t)(lrow + 16) * HIDDEN + kbase);
#pragma unroll
        for (int nt = 0; nt < 4; ++nt) {
            const float* wp = W + (size_t)kbase * N2 + (n0 + nt * 16 + lrow);
            bf16x8 bh, bl;
#pragma unroll
            for (int j = 0; j < 8; ++j) {
                float wf = wp[(size_t)j * N2];
                short h = f2bf(wf);
                bh[j] = h;
                bl[j] = f2bf(wf - bf2f(h));
            }
            acc[0][nt] = __builtin_amdgcn_mfma_f32_16x16x32_bf16(a0h, bh, acc[0][nt], 0, 0, 0);
            acc[1][nt] = __builtin_amdgcn_mfma_f32_16x16x32_bf16(a1h, bh, acc[1][nt], 0, 0, 0);
            acc[0][nt] = __builtin_amdgcn_mfma_f32_16x16x32_bf16(a0l, bh, acc[0][nt], 0, 0, 0);
            acc[1][nt] = __builtin_amdgcn_mfma_f32_16x16x32_bf16(a1l, bh, acc[1][nt], 0, 0, 0);
            acc[0][nt] = __builtin_amdgcn_mfma_f32_16x16x32_bf16(a0h, bl, acc[0][nt], 0, 0, 0);
            acc[1][nt] = __builtin_amdgcn_mfma_f32_16x16x32_bf16(a1h, bl, acc[1][nt], 0, 0, 0);
        }
    }

    float* pb = P + (size_t)kb * pstride + so;
#pragma unroll
    for (int mt = 0; mt < 2; ++mt)
#pragma unroll
        for (int nt = 0; nt < 4; ++nt)
#pragma unroll
            for (int r = 0; r < 4; ++r) {
                int row = mt * 16 + kgrp * 4 + r;
                pb[(size_t)row * N2 + n0 + nt * 16 + lrow] = acc[mt][nt][r];
            }
}

// out[i] = sum_s P[s][i]  (NSPLIT k-split partials)
__global__ __launch_bounds__(256) void reduce_split(const float* __restrict__ P,
                                                    float* __restrict__ out,
                                                    int nelem, size_t pstride) {
    int i = (blockIdx.x * 256 + threadIdx.x) * 4;
    if (i >= nelem) return;
    float4 a = *(const float4*)(P + i);
#pragma unroll 4
    for (int s = 1; s < NSPLIT; ++s) {
        float4 b = *(const float4*)(P + (size_t)s * pstride + i);
        a.x += b.x; a.y += b.y; a.z += b.z; a.w += b.w;
    }
    *(float4*)(out + i) = a;
}

// ---------------------------------------------------------------------------
// Rotary: rows 0..2047 = q rows (32*64), rows 2048..2303 = k rows (32*8).
// ---------------------------------------------------------------------------
#define RROWS 16
__global__ __launch_bounds__(128) void rotary_all(const float* __restrict__ qin,
                                                  const float* __restrict__ kin,
                                                  const float* __restrict__ rot,
                                                  float* __restrict__ qout,
                                                  float* __restrict__ kout) {
    __shared__ float rows[RROWS][HD];
    const int tid = threadIdx.x;
    const int row0 = blockIdx.x * RROWS;

    for (int i = tid; i < RROWS * (HD / 4); i += 128) {
        int r = i >> 5;
        int d4 = i & 31;
        int gr = row0 + r;
        const float* src = (gr < BATCH * NHEADS)
                               ? (qin + (size_t)gr * HD)
                               : (kin + (size_t)(gr - BATCH * NHEADS) * HD);
        *(float4*)&rows[r][d4 * 4] = *(const float4*)(src + d4 * 4);
    }
    __syncthreads();

    float acc[RROWS];
#pragma unroll
    for (int r = 0; r < RROWS; ++r) acc[r] = 0.f;

    for (int d4 = 0; d4 < HD; d4 += 4) {
        float r0 = rot[(size_t)(d4 + 0) * HD + tid];
        float r1 = rot[(size_t)(d4 + 1) * HD + tid];
        float r2 = rot[(size_t)(d4 + 2) * HD + tid];
        float r3 = rot[(size_t)(d4 + 3) * HD + tid];
#pragma unroll
        for (int r = 0; r < RROWS; ++r) {
            float4 xv = *(const float4*)&rows[r][d4];
            acc[r] = fmaf(xv.x, r0, acc[r]);
            acc[r] = fmaf(xv.y, r1, acc[r]);
            acc[r] = fmaf(xv.z, r2, acc[r]);
            acc[r] = fmaf(xv.w, r3, acc[r]);
        }
    }
#pragma unroll
    for (int r = 0; r < RROWS; ++r) {
        int gr = row0 + r;
        float* dst = (gr < BATCH * NHEADS)
                         ? (qout + (size_t)gr * HD)
                         : (kout + (size_t)(gr - BATCH * NHEADS) * HD);
        dst[tid] = acc[r];
    }
}

// ---------------------------------------------------------------------------
// Flash-decode attention, split-KV x4, counted-vmcnt ring pipeline (T4).
// (unchanged from round 5 — 120 us, ~71% of its HBM floor)
// ---------------------------------------------------------------------------
#define TILE 16
#define NBUF 4
__global__ __launch_bounds__(512, 4) void attn_decode(
        const float* __restrict__ qr, const float* __restrict__ kr,
        const float* __restrict__ vnew, const float* __restrict__ kcache,
        const float* __restrict__ vcache, const int* __restrict__ sp_ptr,
        float* __restrict__ part_acc, float* __restrict__ part_md) {
    __shared__ float4 kt[NBUF][TILE][32];
    __shared__ float4 vt[NBUF][TILE][32];

    const int tid = threadIdx.x;
    const int wv = tid >> 6, ln = tid & 63;
    const int row = ln & 15, qd = ln >> 4;      // phase A geometry
    const int dslot = ln & 31, hh = ln >> 5;    // phase B geometry
    const int chunk = blockIdx.x >> 8;
    const int b  = (blockIdx.x >> 3) & 31;
    const int kv = blockIdx.x & 7;
    const int chunk0 = chunk * CHUNKLEN;
    const int sp = sp_ptr[0];
    const float scale = 0.08838834764831845f;   // 1/sqrt(128)
    const int bh = b * NHEADS + kv * 8 + wv;

    const float* kbase = kcache + (size_t)(b * NKV + kv) * PADLEN * HD;
    const float* vbase = vcache + (size_t)(b * NKV + kv) * PADLEN * HD;
    const float* knew  = kr   + (size_t)(b * NKV + kv) * HD;
    const float* vnw   = vnew + (size_t)(b * NKV + kv) * HD;

    float4 qreg[8];
    {
        const float4* qsrc = (const float4*)(qr + (size_t)bh * HD) + qd * 8;
#pragma unroll
        for (int i = 0; i < 8; ++i) qreg[i] = qsrc[i];
    }

    const int sr  = wv * 2 + (ln >> 5);    // staging row 0..15
    const int sj  = ln & 31;
    const int sjk = sj ^ (sr & 7);         // K slot (pre-swizzled src)

    float m_run = -1e30f, dsum = 0.f;
    float4 acc = make_float4(0.f, 0.f, 0.f, 0.f);

    int valid = sp + 1 - chunk0;
    int nt = valid <= 0 ? 0 : (valid + TILE - 1) >> 4;
    if (nt > CHUNKLEN / TILE) nt = CHUNKLEN / TILE;

    auto stage = [&](int ts, int slot) {
        const int gl = chunk0 + (ts << 4) + sr;
        const float* krow = (gl == sp) ? knew : (kbase + (size_t)gl * HD);
        const float* vrow = (gl == sp) ? vnw  : (vbase + (size_t)gl * HD);
        gld16(krow + (sjk << 2), (float*)&kt[slot][0][0] + wv * 256);
        gld16(vrow + (sj  << 2), (float*)&vt[slot][0][0] + wv * 256);
    };

    auto compute = [&](int t) {
        const float4 (*kt_)[32] = kt[t & 3];
        const float4 (*vt_)[32] = vt[t & 3];
        float sh = 0.f;
#pragma unroll
        for (int jj = 0; jj < 8; ++jj) {
            float4 kk = kt_[row][(qd * 8 + jj) ^ (row & 7)];
            float4 qq = qreg[jj];
            sh = fmaf(qq.x, kk.x, sh);
            sh = fmaf(qq.y, kk.y, sh);
            sh = fmaf(qq.z, kk.z, sh);
            sh = fmaf(qq.w, kk.w, sh);
        }
        sh += __shfl_xor(sh, 16);
        sh += __shfl_xor(sh, 32);
        float s0 = sh * scale;
        const int l0 = chunk0 + (t << 4) + row;
        const bool dead = l0 > sp;
        if (dead) s0 = -1e30f;

        float mt = s0;
        mt = fmaxf(mt, __shfl_xor(mt, 1));
        mt = fmaxf(mt, __shfl_xor(mt, 2));
        mt = fmaxf(mt, __shfl_xor(mt, 4));
        mt = fmaxf(mt, __shfl_xor(mt, 8));
        float mnew = fmaxf(m_run, mt);
        float f = __expf(m_run - mnew);
        float p0 = dead ? 0.f : __expf(s0 - mnew);
        m_run = mnew;
        dsum = dsum * f + p0;
        acc.x *= f; acc.y *= f; acc.z *= f; acc.w *= f;

#pragma unroll
        for (int i = 0; i < 8; ++i) {
            float4 vv = vt_[hh * 8 + i][dslot];
            float pa = readlane_f(p0, i);
            float pb = readlane_f(p0, 8 + i);
            float pr = hh ? pb : pa;
            acc.x = fmaf(pr, vv.x, acc.x);
            acc.y = fmaf(pr, vv.y, acc.y);
            acc.z = fmaf(pr, vv.z, acc.z);
            acc.w = fmaf(pr, vv.w, acc.w);
        }
    };

    if (nt > 0) {
        stage(0, 0);
        stage(nt > 1 ? 1 : 0, 1);
        for (int t = 0; t < nt; ++t) {
            int ts = t + 2 < nt ? t + 2 : nt - 1;    // clamped dummy keeps counts uniform
            stage(ts, (t + 2) & 3);
            asm volatile("s_waitcnt vmcnt(4)" ::: "memory");
            __builtin_amdgcn_s_barrier();
            compute(t);
        }
    }

    acc.x += __shfl_xor(acc.x, 32);
    acc.y += __shfl_xor(acc.y, 32);
    acc.z += __shfl_xor(acc.z, 32);
    acc.w += __shfl_xor(acc.w, 32);
    float dd = dsum;
    dd += __shfl_xor(dd, 1);
    dd += __shfl_xor(dd, 2);
    dd += __shfl_xor(dd, 4);
    dd += __shfl_xor(dd, 8);

    if (hh == 0)
        *(float4*)(part_acc + ((size_t)chunk * (BATCH * NHEADS) + bh) * HD + dslot * 4) = acc;
    if (ln == 0) {
        float2 md = make_float2(m_run, dd);
        *(float2*)(part_md + ((size_t)chunk * (BATCH * NHEADS) + bh) * 2) = md;
    }
}

// merge the NCHUNK split-KV partials per head
__global__ __launch_bounds__(128) void attn_combine(const float* __restrict__ part_acc,
                                                    const float* __restrict__ part_md,
                                                    float* __restrict__ attn_out) {
    const int bh = blockIdx.x;
    const int d = threadIdx.x;
    float m[NCHUNK], dd[NCHUNK];
    float M = -1e30f;
#pragma unroll
    for (int c = 0; c < NCHUNK; ++c) {
        m[c]  = part_md[((size_t)c * (BATCH * NHEADS) + bh) * 2];
        dd[c] = part_md[((size_t)c * (BATCH * NHEADS) + bh) * 2 + 1];
        M = fmaxf(M, m[c]);
    }
    float D = 0.f, o = 0.f;
#pragma unroll
    for (int c = 0; c < NCHUNK; ++c) {
        float w = __expf(m[c] - M);
        D += dd[c] * w;
        o += part_acc[((size_t)c * (BATCH * NHEADS) + bh) * HD + d] * w;
    }
    attn_out[(size_t)bh * HD + d] = o / D;
}

// ---------------------------------------------------------------------------
extern "C" void kernel_launch(void* const* d_in, const int* in_sizes, int n_in,
                              void* d_out, int out_size, void* d_ws, size_t ws_size,
                              hipStream_t stream) {
    const float* x   = (const float*)d_in[0];
    const float* wq  = (const float*)d_in[1];
    const float* wk  = (const float*)d_in[2];
    const float* wv  = (const float*)d_in[3];
    const float* wo  = (const float*)d_in[4];
    const float* rot = (const float*)d_in[5];
    const float* kc  = (const float*)d_in[6];
    const float* vc  = (const float*)d_in[7];
    const int*   sp  = (const int*)d_in[8];
    float* out = (float*)d_out;

    float* ws = (float*)d_ws;
    float* qkv_buf  = ws;                    // q 262144 | k 32768 | v 32768
    float* q_buf    = qkv_buf;
    float* k_buf    = qkv_buf + QSEC;
    float* v_buf    = qkv_buf + KSEC;
    float* qr_buf   = ws + 327680;           // 262144
    float* kr_buf   = ws + 589824;           // 32768
    float* attn_buf = ws + 622592;           // 262144
    short* xhi      = (short*)(ws + 884736);           // 262144 bf16 = 131072 f
    short* xlo      = (short*)(ws + 884736 + 131072);
    short* ahi      = (short*)(ws + 884736 + 262144);
    short* alo      = (short*)(ws + 884736 + 393216);
    float* P        = ws + 884736 + 524288;  // 16 * 327680 partials
    // split-KV partials overlay P (P consumed before attn, reused after)
    float* part_acc = P;                     // 4*2048*128 = 1048576
    float* part_md  = P + 1048576;           // 4*2048*2   = 16384

    // QKV projection: split x -> MFMA GEMM (k-split partials) -> reduce
    cvt_split<<<(QSEC / 4 + 255) / 256, 256, 0, stream>>>(x, xhi, xlo, QSEC / 4);
    gemm_mfma<<<dim3(40, NSPLIT), 256, 0, stream>>>(xhi, xlo, wq, wk, wv, P, QKV_STRIDE);
    reduce_split<<<(QKV_STRIDE / 4 + 255) / 256, 256, 0, stream>>>(
        P, qkv_buf, QKV_STRIDE, QKV_STRIDE);

    // rotary on q and k
    rotary_all<<<(BATCH * NHEADS + BATCH * NKV) / RROWS, 128, 0, stream>>>(
        q_buf, k_buf, rot, qr_buf, kr_buf);

    // attention (split-KV) + combine
    attn_decode<<<NCHUNK * BATCH * NKV, 512, 0, stream>>>(
        qr_buf, kr_buf, v_buf, kc, vc, sp, part_acc, part_md);
    attn_combine<<<BATCH * NHEADS, 128, 0, stream>>>(part_acc, part_md, attn_buf);

    // output projection: split attn -> MFMA GEMM -> reduce into d_out
    cvt_split<<<(QSEC / 4 + 255) / 256, 256, 0, stream>>>(attn_buf, ahi, alo, QSEC / 4);
    gemm_mfma<<<dim3(32, NSPLIT), 256, 0, stream>>>(ahi, alo, wo, wo, wo, P, QSEC);
    reduce_split<<<(QSEC / 4 + 255) / 256, 256, 0, stream>>>(P, out, QSEC, QSEC);
}

// Round 7
// 302.514 us; speedup vs baseline: 1.9392x; 1.0027x over previous
//
#include <hip/hip_runtime.h>
#include <hip/hip_bf16.h>

#define HIDDEN 8192
#define NHEADS 64
#define NKV 8
#define HD 128
#define BATCH 32
#define PADLEN 2048
#define NCHUNK 4
#define CHUNKLEN 512

using bf16x8 = __attribute__((ext_vector_type(8))) short;
using f32x4 = __attribute__((ext_vector_type(4))) float;

// ---------------------------------------------------------------------------
// helpers
// ---------------------------------------------------------------------------
__device__ __forceinline__ void gld16(const float* g, float* l) {
    __builtin_amdgcn_global_load_lds(
        (const __attribute__((address_space(1))) void*)g,
        (__attribute__((address_space(3))) void*)l,
        16, 0, 0);
}

// readlane for float: bitcast, NOT value conversion (builtin is (uint,uint)!)
__device__ __forceinline__ float readlane_f(float v, int lane) {
    return __uint_as_float(__builtin_amdgcn_readlane(__float_as_uint(v), lane));
}

__device__ __forceinline__ short f2bf(float f) {      // RNE f32->bf16
    unsigned u = __float_as_uint(f);
    u += 0x7fff + ((u >> 16) & 1);
    return (short)(u >> 16);
}
__device__ __forceinline__ float bf2f(short s) {
    return __uint_as_float(((unsigned)(unsigned short)s) << 16);
}

// ---------------------------------------------------------------------------
// split a f32 vector into hi/lo bf16 (x = hi + lo, residual ~2^-17 rel)
// ---------------------------------------------------------------------------
__global__ __launch_bounds__(256) void cvt_split(const float* __restrict__ in,
                                                 short* __restrict__ hi,
                                                 short* __restrict__ lo, int n4) {
    int i = blockIdx.x * 256 + threadIdx.x;
    if (i >= n4) return;
    float4 v = ((const float4*)in)[i];
    short4 h, l;
    h.x = f2bf(v.x); l.x = f2bf(v.x - bf2f(h.x));
    h.y = f2bf(v.y); l.y = f2bf(v.y - bf2f(h.y));
    h.z = f2bf(v.z); l.z = f2bf(v.z - bf2f(h.z));
    h.w = f2bf(v.w); l.w = f2bf(v.w - bf2f(h.w));
    ((short4*)hi)[i] = h;
    ((short4*)lo)[i] = l;
}

// ---------------------------------------------------------------------------
// MFMA split-bf16 skinny GEMM, software-pipelined, grid-aligned.
// P[kb] = X[32][K-slice] @ {W0|W1|W2}; X pre-split bf16 hi/lo; W streamed
// f32, split in-register; 3 MFMA passes (xh*wh + xl*wh + xh*wl).
// Block 256 thr = 4 waves; wave covers 32 cols (2 n-tiles of 16).
// QKV: 80 cb x 16 kb = 1280 blocks = 5.0/CU; wo: 64 x 16 = 1024 = 4.0/CU.
// One-step register prefetch of A-fragments + raw B floats hides HBM latency
// behind the MFMA cluster; all indices compile-time (rule #20).
// ---------------------------------------------------------------------------
#define QSEC 262144          // 32*8192
#define KSEC 294912          // QSEC + 32*1024
#define QKV_STRIDE 327680    // QSEC + 2*32*1024
#define NSPLIT 16
#define KSLICE 512           // HIDDEN / NSPLIT

__global__ __launch_bounds__(256) void gemm_mfma(
        const short* __restrict__ xhi, const short* __restrict__ xlo,
        const float* __restrict__ W0, const float* __restrict__ W1,
        const float* __restrict__ W2, float* __restrict__ P, size_t pstride) {
    const int tid = threadIdx.x;
    const int wv = tid >> 6, ln = tid & 63;
    const int cb = blockIdx.x, kb = blockIdx.y;

    const float* W; int N2; size_t so; int nbase;
    if (cb < 64)      { W = W0; N2 = 8192; so = 0;    nbase = cb * 128; }
    else if (cb < 72) { W = W1; N2 = 1024; so = QSEC; nbase = (cb - 64) * 128; }
    else              { W = W2; N2 = 1024; so = KSEC; nbase = (cb - 72) * 128; }

    const int n0 = nbase + wv * 32;      // this wave: cols n0..n0+31
    const int lrow = ln & 15;
    const int kgrp = ln >> 4;
    const int k0 = kb * KSLICE;

    // column/base pointers (k advances via index)
    const float* wp0 = W + (size_t)(k0 + kgrp * 8) * N2 + (n0 + lrow);
    const float* wp1 = wp0 + 16;
    const short* xh0 = xhi + (size_t)lrow * HIDDEN + k0 + kgrp * 8;
    const short* xl0 = xlo + (size_t)lrow * HIDDEN + k0 + kgrp * 8;
    const short* xh1 = xh0 + (size_t)16 * HIDDEN;
    const short* xl1 = xl0 + (size_t)16 * HIDDEN;

    f32x4 acc00 = {0.f,0.f,0.f,0.f}, acc01 = {0.f,0.f,0.f,0.f};
    f32x4 acc10 = {0.f,0.f,0.f,0.f}, acc11 = {0.f,0.f,0.f,0.f};

    float c0[8], c1[8], pb0[8], pb1[8];
    bf16x8 A0h, A0l, A1h, A1l, N0h, N0l, N1h, N1l;

    auto loadB = [&](int kk, float (&b0)[8], float (&b1)[8]) {
#pragma unroll
        for (int j = 0; j < 8; ++j) {
            b0[j] = wp0[(size_t)(kk + j) * N2];
            b1[j] = wp1[(size_t)(kk + j) * N2];
        }
    };
    auto loadA = [&](int kk, bf16x8& h0, bf16x8& l0, bf16x8& h1, bf16x8& l1) {
        h0 = *(const bf16x8*)(xh0 + kk);
        l0 = *(const bf16x8*)(xl0 + kk);
        h1 = *(const bf16x8*)(xh1 + kk);
        l1 = *(const bf16x8*)(xl1 + kk);
    };
    auto domfma = [&](float (&b0)[8], float (&b1)[8],
                      bf16x8 ah0, bf16x8 al0, bf16x8 ah1, bf16x8 al1) {
        bf16x8 bh0, bl0, bh1, bl1;
#pragma unroll
        for (int j = 0; j < 8; ++j) {
            short h0 = f2bf(b0[j]); bh0[j] = h0; bl0[j] = f2bf(b0[j] - bf2f(h0));
            short h1 = f2bf(b1[j]); bh1[j] = h1; bl1[j] = f2bf(b1[j] - bf2f(h1));
        }
        acc00 = __builtin_amdgcn_mfma_f32_16x16x32_bf16(ah0, bh0, acc00, 0, 0, 0);
        acc10 = __builtin_amdgcn_mfma_f32_16x16x32_bf16(ah1, bh0, acc10, 0, 0, 0);
        acc01 = __builtin_amdgcn_mfma_f32_16x16x32_bf16(ah0, bh1, acc01, 0, 0, 0);
        acc11 = __builtin_amdgcn_mfma_f32_16x16x32_bf16(ah1, bh1, acc11, 0, 0, 0);
        acc00 = __builtin_amdgcn_mfma_f32_16x16x32_bf16(al0, bh0, acc00, 0, 0, 0);
        acc10 = __builtin_amdgcn_mfma_f32_16x16x32_bf16(al1, bh0, acc10, 0, 0, 0);
        acc01 = __builtin_amdgcn_mfma_f32_16x16x32_bf16(al0, bh1, acc01, 0, 0, 0);
        acc11 = __builtin_amdgcn_mfma_f32_16x16x32_bf16(al1, bh1, acc11, 0, 0, 0);
        acc00 = __builtin_amdgcn_mfma_f32_16x16x32_bf16(ah0, bl0, acc00, 0, 0, 0);
        acc10 = __builtin_amdgcn_mfma_f32_16x16x32_bf16(ah1, bl0, acc10, 0, 0, 0);
        acc01 = __builtin_amdgcn_mfma_f32_16x16x32_bf16(ah0, bl1, acc01, 0, 0, 0);
        acc11 = __builtin_amdgcn_mfma_f32_16x16x32_bf16(ah1, bl1, acc11, 0, 0, 0);
    };

    loadB(0, c0, c1);
    loadA(0, A0h, A0l, A1h, A1l);
#pragma unroll
    for (int kk = 0; kk < KSLICE - 32; kk += 32) {
        loadB(kk + 32, pb0, pb1);
        loadA(kk + 32, N0h, N0l, N1h, N1l);
        domfma(c0, c1, A0h, A0l, A1h, A1l);
#pragma unroll
        for (int j = 0; j < 8; ++j) { c0[j] = pb0[j]; c1[j] = pb1[j]; }
        A0h = N0h; A0l = N0l; A1h = N1h; A1l = N1l;
    }
    domfma(c0, c1, A0h, A0l, A1h, A1l);

    // C/D: col = l&15, row = (l>>4)*4 + reg (m89-verified)
    float* pb = P + (size_t)kb * pstride + so;
#pragma unroll
    for (int r = 0; r < 4; ++r) {
        int row0 = kgrp * 4 + r;
        pb[(size_t)row0 * N2 + n0 + lrow]            = acc00[r];
        pb[(size_t)row0 * N2 + n0 + 16 + lrow]       = acc01[r];
        pb[(size_t)(row0 + 16) * N2 + n0 + lrow]      = acc10[r];
        pb[(size_t)(row0 + 16) * N2 + n0 + 16 + lrow] = acc11[r];
    }
}

// out[i] = sum_s P[s][i]  (NSPLIT k-split partials)
__global__ __launch_bounds__(256) void reduce_split(const float* __restrict__ P,
                                                    float* __restrict__ out,
                                                    int nelem, size_t pstride) {
    int i = (blockIdx.x * 256 + threadIdx.x) * 4;
    if (i >= nelem) return;
    float4 a = *(const float4*)(P + i);
#pragma unroll 4
    for (int s = 1; s < NSPLIT; ++s) {
        float4 b = *(const float4*)(P + (size_t)s * pstride + i);
        a.x += b.x; a.y += b.y; a.z += b.z; a.w += b.w;
    }
    *(float4*)(out + i) = a;
}

// ---------------------------------------------------------------------------
// Rotary: rows 0..2047 = q rows (32*64), rows 2048..2303 = k rows (32*8).
// ---------------------------------------------------------------------------
#define RROWS 16
__global__ __launch_bounds__(128) void rotary_all(const float* __restrict__ qin,
                                                  const float* __restrict__ kin,
                                                  const float* __restrict__ rot,
                                                  float* __restrict__ qout,
                                                  float* __restrict__ kout) {
    __shared__ float rows[RROWS][HD];
    const int tid = threadIdx.x;
    const int row0 = blockIdx.x * RROWS;

    for (int i = tid; i < RROWS * (HD / 4); i += 128) {
        int r = i >> 5;
        int d4 = i & 31;
        int gr = row0 + r;
        const float* src = (gr < BATCH * NHEADS)
                               ? (qin + (size_t)gr * HD)
                               : (kin + (size_t)(gr - BATCH * NHEADS) * HD);
        *(float4*)&rows[r][d4 * 4] = *(const float4*)(src + d4 * 4);
    }
    __syncthreads();

    float acc[RROWS];
#pragma unroll
    for (int r = 0; r < RROWS; ++r) acc[r] = 0.f;

    for (int d4 = 0; d4 < HD; d4 += 4) {
        float r0 = rot[(size_t)(d4 + 0) * HD + tid];
        float r1 = rot[(size_t)(d4 + 1) * HD + tid];
        float r2 = rot[(size_t)(d4 + 2) * HD + tid];
        float r3 = rot[(size_t)(d4 + 3) * HD + tid];
#pragma unroll
        for (int r = 0; r < RROWS; ++r) {
            float4 xv = *(const float4*)&rows[r][d4];
            acc[r] = fmaf(xv.x, r0, acc[r]);
            acc[r] = fmaf(xv.y, r1, acc[r]);
            acc[r] = fmaf(xv.z, r2, acc[r]);
            acc[r] = fmaf(xv.w, r3, acc[r]);
        }
    }
#pragma unroll
    for (int r = 0; r < RROWS; ++r) {
        int gr = row0 + r;
        float* dst = (gr < BATCH * NHEADS)
                         ? (qout + (size_t)gr * HD)
                         : (kout + (size_t)(gr - BATCH * NHEADS) * HD);
        dst[tid] = acc[r];
    }
}

// ---------------------------------------------------------------------------
// Flash-decode attention, split-KV x4, counted-vmcnt ring pipeline (T4).
// (unchanged — ~121 us)
// ---------------------------------------------------------------------------
#define TILE 16
#define NBUF 4
__global__ __launch_bounds__(512, 4) void attn_decode(
        const float* __restrict__ qr, const float* __restrict__ kr,
        const float* __restrict__ vnew, const float* __restrict__ kcache,
        const float* __restrict__ vcache, const int* __restrict__ sp_ptr,
        float* __restrict__ part_acc, float* __restrict__ part_md) {
    __shared__ float4 kt[NBUF][TILE][32];
    __shared__ float4 vt[NBUF][TILE][32];

    const int tid = threadIdx.x;
    const int wv = tid >> 6, ln = tid & 63;
    const int row = ln & 15, qd = ln >> 4;      // phase A geometry
    const int dslot = ln & 31, hh = ln >> 5;    // phase B geometry
    const int chunk = blockIdx.x >> 8;
    const int b  = (blockIdx.x >> 3) & 31;
    const int kv = blockIdx.x & 7;
    const int chunk0 = chunk * CHUNKLEN;
    const int sp = sp_ptr[0];
    const float scale = 0.08838834764831845f;   // 1/sqrt(128)
    const int bh = b * NHEADS + kv * 8 + wv;

    const float* kbase = kcache + (size_t)(b * NKV + kv) * PADLEN * HD;
    const float* vbase = vcache + (size_t)(b * NKV + kv) * PADLEN * HD;
    const float* knew  = kr   + (size_t)(b * NKV + kv) * HD;
    const float* vnw   = vnew + (size_t)(b * NKV + kv) * HD;

    float4 qreg[8];
    {
        const float4* qsrc = (const float4*)(qr + (size_t)bh * HD) + qd * 8;
#pragma unroll
        for (int i = 0; i < 8; ++i) qreg[i] = qsrc[i];
    }

    const int sr  = wv * 2 + (ln >> 5);    // staging row 0..15
    const int sj  = ln & 31;
    const int sjk = sj ^ (sr & 7);         // K slot (pre-swizzled src)

    float m_run = -1e30f, dsum = 0.f;
    float4 acc = make_float4(0.f, 0.f, 0.f, 0.f);

    int valid = sp + 1 - chunk0;
    int nt = valid <= 0 ? 0 : (valid + TILE - 1) >> 4;
    if (nt > CHUNKLEN / TILE) nt = CHUNKLEN / TILE;

    auto stage = [&](int ts, int slot) {
        const int gl = chunk0 + (ts << 4) + sr;
        const float* krow = (gl == sp) ? knew : (kbase + (size_t)gl * HD);
        const float* vrow = (gl == sp) ? vnw  : (vbase + (size_t)gl * HD);
        gld16(krow + (sjk << 2), (float*)&kt[slot][0][0] + wv * 256);
        gld16(vrow + (sj  << 2), (float*)&vt[slot][0][0] + wv * 256);
    };

    auto compute = [&](int t) {
        const float4 (*kt_)[32] = kt[t & 3];
        const float4 (*vt_)[32] = vt[t & 3];
        float sh = 0.f;
#pragma unroll
        for (int jj = 0; jj < 8; ++jj) {
            float4 kk = kt_[row][(qd * 8 + jj) ^ (row & 7)];
            float4 qq = qreg[jj];
            sh = fmaf(qq.x, kk.x, sh);
            sh = fmaf(qq.y, kk.y, sh);
            sh = fmaf(qq.z, kk.z, sh);
            sh = fmaf(qq.w, kk.w, sh);
        }
        sh += __shfl_xor(sh, 16);
        sh += __shfl_xor(sh, 32);
        float s0 = sh * scale;
        const int l0 = chunk0 + (t << 4) + row;
        const bool dead = l0 > sp;
        if (dead) s0 = -1e30f;

        float mt = s0;
        mt = fmaxf(mt, __shfl_xor(mt, 1));
        mt = fmaxf(mt, __shfl_xor(mt, 2));
        mt = fmaxf(mt, __shfl_xor(mt, 4));
        mt = fmaxf(mt, __shfl_xor(mt, 8));
        float mnew = fmaxf(m_run, mt);
        float f = __expf(m_run - mnew);
        float p0 = dead ? 0.f : __expf(s0 - mnew);
        m_run = mnew;
        dsum = dsum * f + p0;
        acc.x *= f; acc.y *= f; acc.z *= f; acc.w *= f;

#pragma unroll
        for (int i = 0; i < 8; ++i) {
            float4 vv = vt_[hh * 8 + i][dslot];
            float pa = readlane_f(p0, i);
            float pb = readlane_f(p0, 8 + i);
            float pr = hh ? pb : pa;
            acc.x = fmaf(pr, vv.x, acc.x);
            acc.y = fmaf(pr, vv.y, acc.y);
            acc.z = fmaf(pr, vv.z, acc.z);
            acc.w = fmaf(pr, vv.w, acc.w);
        }
    };

    if (nt > 0) {
        stage(0, 0);
        stage(nt > 1 ? 1 : 0, 1);
        for (int t = 0; t < nt; ++t) {
            int ts = t + 2 < nt ? t + 2 : nt - 1;    // clamped dummy keeps counts uniform
            stage(ts, (t + 2) & 3);
            asm volatile("s_waitcnt vmcnt(4)" ::: "memory");
            __builtin_amdgcn_s_barrier();
            compute(t);
        }
    }

    acc.x += __shfl_xor(acc.x, 32);
    acc.y += __shfl_xor(acc.y, 32);
    acc.z += __shfl_xor(acc.z, 32);
    acc.w += __shfl_xor(acc.w, 32);
    float dd = dsum;
    dd += __shfl_xor(dd, 1);
    dd += __shfl_xor(dd, 2);
    dd += __shfl_xor(dd, 4);
    dd += __shfl_xor(dd, 8);

    if (hh == 0)
        *(float4*)(part_acc + ((size_t)chunk * (BATCH * NHEADS) + bh) * HD + dslot * 4) = acc;
    if (ln == 0) {
        float2 md = make_float2(m_run, dd);
        *(float2*)(part_md + ((size_t)chunk * (BATCH * NHEADS) + bh) * 2) = md;
    }
}

// merge the NCHUNK split-KV partials per head
__global__ __launch_bounds__(128) void attn_combine(const float* __restrict__ part_acc,
                                                    const float* __restrict__ part_md,
                                                    float* __restrict__ attn_out) {
    const int bh = blockIdx.x;
    const int d = threadIdx.x;
    float m[NCHUNK], dd[NCHUNK];
    float M = -1e30f;
#pragma unroll
    for (int c = 0; c < NCHUNK; ++c) {
        m[c]  = part_md[((size_t)c * (BATCH * NHEADS) + bh) * 2];
        dd[c] = part_md[((size_t)c * (BATCH * NHEADS) + bh) * 2 + 1];
        M = fmaxf(M, m[c]);
    }
    float D = 0.f, o = 0.f;
#pragma unroll
    for (int c = 0; c < NCHUNK; ++c) {
        float w = __expf(m[c] - M);
        D += dd[c] * w;
        o += part_acc[((size_t)c * (BATCH * NHEADS) + bh) * HD + d] * w;
    }
    attn_out[(size_t)bh * HD + d] = o / D;
}

// ---------------------------------------------------------------------------
extern "C" void kernel_launch(void* const* d_in, const int* in_sizes, int n_in,
                              void* d_out, int out_size, void* d_ws, size_t ws_size,
                              hipStream_t stream) {
    const float* x   = (const float*)d_in[0];
    const float* wq  = (const float*)d_in[1];
    const float* wk  = (const float*)d_in[2];
    const float* wv  = (const float*)d_in[3];
    const float* wo  = (const float*)d_in[4];
    const float* rot = (const float*)d_in[5];
    const float* kc  = (const float*)d_in[6];
    const float* vc  = (const float*)d_in[7];
    const int*   sp  = (const int*)d_in[8];
    float* out = (float*)d_out;

    float* ws = (float*)d_ws;
    float* qkv_buf  = ws;                    // q 262144 | k 32768 | v 32768
    float* q_buf    = qkv_buf;
    float* k_buf    = qkv_buf + QSEC;
    float* v_buf    = qkv_buf + KSEC;
    float* qr_buf   = ws + 327680;           // 262144
    float* kr_buf   = ws + 589824;           // 32768
    float* attn_buf = ws + 622592;           // 262144
    short* xhi      = (short*)(ws + 884736);           // 262144 bf16 = 131072 f
    short* xlo      = (short*)(ws + 884736 + 131072);
    short* ahi      = (short*)(ws + 884736 + 262144);
    short* alo      = (short*)(ws + 884736 + 393216);
    float* P        = ws + 884736 + 524288;  // 16 * 327680 partials
    // split-KV partials overlay P (P consumed before attn, reused after)
    float* part_acc = P;                     // 4*2048*128 = 1048576
    float* part_md  = P + 1048576;           // 4*2048*2   = 16384

    // QKV projection: split x -> MFMA GEMM (k-split partials) -> reduce
    cvt_split<<<(QSEC / 4 + 255) / 256, 256, 0, stream>>>(x, xhi, xlo, QSEC / 4);
    gemm_mfma<<<dim3(80, NSPLIT), 256, 0, stream>>>(xhi, xlo, wq, wk, wv, P, QKV_STRIDE);
    reduce_split<<<(QKV_STRIDE / 4 + 255) / 256, 256, 0, stream>>>(
        P, qkv_buf, QKV_STRIDE, QKV_STRIDE);

    // rotary on q and k
    rotary_all<<<(BATCH * NHEADS + BATCH * NKV) / RROWS, 128, 0, stream>>>(
        q_buf, k_buf, rot, qr_buf, kr_buf);

    // attention (split-KV) + combine
    attn_decode<<<NCHUNK * BATCH * NKV, 512, 0, stream>>>(
        qr_buf, kr_buf, v_buf, kc, vc, sp, part_acc, part_md);
    attn_combine<<<BATCH * NHEADS, 128, 0, stream>>>(part_acc, part_md, attn_buf);

    // output projection: split attn -> MFMA GEMM -> reduce into d_out
    cvt_split<<<(QSEC / 4 + 255) / 256, 256, 0, stream>>>(attn_buf, ahi, alo, QSEC / 4);
    gemm_mfma<<<dim3(64, NSPLIT), 256, 0, stream>>>(ahi, alo, wo, wo, wo, P, QSEC);
    reduce_split<<<(QSEC / 4 + 255) / 256, 256, 0, stream>>>(P, out, QSEC, QSEC);
}